// Round 3
// baseline (41.482 us; speedup 1.0000x reference)
//
#include <hip/hip_runtime.h>
#include <math.h>

#define NB 8
#define PP 4096
#define MM 2048
#define DIRS 2
#define QSLICES 16
#define QS (PP / QSLICES)       // 256 q's staged per block
#define PCHUNK 1024             // p's per block (256 threads x 4)
#define NPBLK (PP / PCHUNK)     // 4
#define NMIN (DIRS * NB * PP)   // 65536 slots
#define NLIK (NB * MM)          // 16384

// ---------------- chamfer partial mins (non-atomic planes) ----------------
// grid = 2*8*4*16 = 1024 blocks x 256 threads. Each thread owns 4 p's,
// scans a 256-q LDS slice, writes (min + |x|^2) to plane wspart[qs][slot].
__global__ __launch_bounds__(256, 4) void chamfer_kernel(const float* __restrict__ x,
                                                         const float* __restrict__ y,
                                                         float* __restrict__ wspart) {
    int bx = blockIdx.x;
    int qs  = bx & (QSLICES - 1); bx >>= 4;
    int pc  = bx & (NPBLK - 1);   bx >>= 2;
    int n   = bx & (NB - 1);      bx >>= 3;
    int dir = bx;
    const float* a = dir ? y : x;
    const float* b = dir ? x : y;
    const float* an = a + (size_t)n * PP * 3;
    const float* bn = b + (size_t)n * PP * 3;

    __shared__ float4 lds[QS];   // 4 KiB: {-2*y0, -2*y1, -2*y2, |y|^2}
    int t = threadIdx.x;
    {
        int q = qs * QS + t;     // QS == 256 == blockDim.x
        const float* bp = bn + (size_t)q * 3;
        float y0 = bp[0], y1 = bp[1], y2 = bp[2];
        lds[t] = make_float4(-2.f * y0, -2.f * y1, -2.f * y2,
                             y0 * y0 + y1 * y1 + y2 * y2);
    }

    float X0[4], X1[4], X2[4], XS[4], M[4];
    #pragma unroll
    for (int i = 0; i < 4; ++i) {
        int p = pc * PCHUNK + i * 256 + t;
        const float* ap = an + (size_t)p * 3;
        X0[i] = ap[0]; X1[i] = ap[1]; X2[i] = ap[2];
        XS[i] = X0[i] * X0[i] + X1[i] * X1[i] + X2[i] * X2[i];
        M[i] = INFINITY;
    }
    __syncthreads();

    #pragma unroll 4
    for (int q = 0; q < QS; q += 2) {
        float4 v0 = lds[q];
        float4 v1 = lds[q + 1];
        #pragma unroll
        for (int i = 0; i < 4; ++i) {
            float d0 = fmaf(X0[i], v0.x, fmaf(X1[i], v0.y, fmaf(X2[i], v0.z, v0.w)));
            float d1 = fmaf(X0[i], v1.x, fmaf(X1[i], v1.y, fmaf(X2[i], v1.z, v1.w)));
            M[i] = fminf(fminf(M[i], d0), d1);   // hopefully v_min3_f32
        }
    }

    float* plane = wspart + (size_t)qs * NMIN;
    int slot = (dir * NB + n) * PP + pc * PCHUNK + t;
    #pragma unroll
    for (int i = 0; i < 4; ++i)
        plane[slot + i * 256] = M[i] + XS[i];   // coalesced, no atomics, no init
}

// ---------------- reduce planes + log2sum + finalize (fused) ----------------
// grid = 256 blocks x 256 threads; slot t = blockIdx.x*256+threadIdx.x.
// Blocks 0..127 cover dir0 slots, 128..255 dir1. Blocks 0..63 also do log2.
// Last-done block finalizes the 5 outputs.
__global__ __launch_bounds__(256) void reduce_kernel(const float* __restrict__ wspart,
                                                     const float* __restrict__ lik,
                                                     float* __restrict__ wssum,  // [0],[1],[2]=sums, [3]=ticket
                                                     float* __restrict__ out) {
    int t = blockIdx.x * 256 + threadIdx.x;
    float m = wspart[t];
    #pragma unroll
    for (int s = 1; s < QSLICES; ++s)
        m = fminf(m, wspart[(size_t)s * NMIN + t]);

    float l = 0.f;
    if (t < NLIK) l = __log2f(lik[t]);

    #pragma unroll
    for (int off = 32; off > 0; off >>= 1) {
        m += __shfl_down(m, off, 64);
        l += __shfl_down(l, off, 64);
    }
    __shared__ float rm[4], rl[4];
    int lane = threadIdx.x & 63, wid = threadIdx.x >> 6;
    if (lane == 0) { rm[wid] = m; rl[wid] = l; }
    __syncthreads();
    if (threadIdx.x == 0) {
        int dir = blockIdx.x >> 7;
        atomicAdd(&wssum[dir], rm[0] + rm[1] + rm[2] + rm[3]);
        if (blockIdx.x < 64)
            atomicAdd(&wssum[2], rl[0] + rl[1] + rl[2] + rl[3]);
        __threadfence();
        unsigned done = atomicAdd((unsigned*)&wssum[3], 1u);
        if (done == 255u) {
            __threadfence();
            float s0 = __hip_atomic_load(&wssum[0], __ATOMIC_ACQUIRE, __HIP_MEMORY_SCOPE_AGENT);
            float s1 = __hip_atomic_load(&wssum[1], __ATOMIC_ACQUIRE, __HIP_MEMORY_SCOPE_AGENT);
            float s2 = __hip_atomic_load(&wssum[2], __ATOMIC_ACQUIRE, __HIP_MEMORY_SCOPE_AGENT);
            float rec = s0 / (float)(NB * PP) + s1 / (float)(NB * PP);
            float bit_y = s2 / (-(float)NB);
            float bpp = bit_y / (float)PP;
            out[0] = bpp + 1.0f * rec;  // loss (LMBDA = 1)
            out[1] = bpp;               // bpp_loss
            out[2] = rec;               // rec_loss
            out[3] = bit_y;             // bit_loss
            out[4] = bpp;               // bpp_y
        }
    }
}

extern "C" void kernel_launch(void* const* d_in, const int* in_sizes, int n_in,
                              void* d_out, int out_size, void* d_ws, size_t ws_size,
                              hipStream_t stream) {
    const float* x_hat  = (const float*)d_in[0];
    const float* points = (const float*)d_in[1];
    const float* lik    = (const float*)d_in[2];
    float* out = (float*)d_out;
    float* wssum  = (float*)d_ws;          // 4 floats: sums + ticket
    float* wspart = (float*)d_ws + 16;     // 16 planes x 65536 floats = 4 MB

    hipMemsetAsync(wssum, 0, 16, stream);  // sums + ticket only
    chamfer_kernel<<<DIRS * NB * NPBLK * QSLICES, 256, 0, stream>>>(x_hat, points, wspart);
    reduce_kernel<<<256, 256, 0, stream>>>(wspart, lik, wssum, out);
}

// Round 4
// 41.081 us; speedup vs baseline: 1.0098x; 1.0098x over previous
//
#include <hip/hip_runtime.h>
#include <math.h>

#define NB 8
#define PP 4096
#define MM 2048
#define DIRS 2
#define QSLICES 16
#define QS (PP / QSLICES)       // 256 q's staged per block
#define NPTS 8                  // points per thread
#define PCHUNK (256 * NPTS)     // 2048 p's per block
#define NPBLK (PP / PCHUNK)     // 2
#define NMIN (DIRS * NB * PP)   // 65536 slots
#define NLIK (NB * MM)          // 16384

typedef float v2f __attribute__((ext_vector_type(2)));

// ---------------- chamfer partial mins (non-atomic planes) ----------------
// grid = 2*8*2*16 = 512 blocks x 256 threads. Each thread owns 8 p's,
// scans a 256-q LDS slice (pk-paired layout), writes (min + |x|^2) to
// plane wspart[qs][slot].
__global__ __launch_bounds__(256, 2) void chamfer_kernel(const float* __restrict__ x,
                                                         const float* __restrict__ y,
                                                         float* __restrict__ wspart) {
    int bx = blockIdx.x;
    int qs  = bx & (QSLICES - 1); bx >>= 4;
    int pc  = bx & (NPBLK - 1);   bx >>= 1;
    int n   = bx & (NB - 1);      bx >>= 3;
    int dir = bx;
    const float* a = dir ? y : x;
    const float* b = dir ? x : y;
    const float* an = a + (size_t)n * PP * 3;
    const float* bn = b + (size_t)n * PP * 3;

    // pk-pair layout: lds[2j]   = {-2y0[2j], -2y0[2j+1], -2y1[2j], -2y1[2j+1]}
    //                 lds[2j+1] = {-2y2[2j], -2y2[2j+1],  ys[2j],   ys[2j+1]}
    __shared__ float4 lds[QS * 2 / 2 * 2];   // 256 float4 = 4 KiB
    int t = threadIdx.x;

    // load my 8 x-points first (overlaps with staging)
    float X0[NPTS], X1[NPTS], X2[NPTS], XS[NPTS], M[NPTS];
    #pragma unroll
    for (int i = 0; i < NPTS; ++i) {
        int p = pc * PCHUNK + i * 256 + t;
        const float* ap = an + (size_t)p * 3;
        X0[i] = ap[0]; X1[i] = ap[1]; X2[i] = ap[2];
        XS[i] = X0[i] * X0[i] + X1[i] * X1[i] + X2[i] * X2[i];
        M[i] = INFINITY;
    }

    {   // stage q-slice: thread t -> q = qs*256 + t, pair j = t>>1, parity = t&1
        int q = qs * QS + t;
        const float* bp = bn + (size_t)q * 3;
        float y0 = bp[0], y1 = bp[1], y2 = bp[2];
        int j = t >> 1, par = t & 1;
        float* base = (float*)&lds[2 * j];
        base[0 + par] = -2.f * y0;
        base[2 + par] = -2.f * y1;
        base[4 + par] = -2.f * y2;
        base[6 + par] = y0 * y0 + y1 * y1 + y2 * y2;
    }
    __syncthreads();

    #pragma unroll 2
    for (int j = 0; j < QS / 2; ++j) {
        float4 A = lds[2 * j];
        float4 B = lds[2 * j + 1];
        v2f Y0 = {A.x, A.y}, Y1 = {A.z, A.w}, Y2 = {B.x, B.y}, YS = {B.z, B.w};
        #pragma unroll
        for (int i = 0; i < NPTS; ++i) {
            v2f x0 = {X0[i], X0[i]}, x1 = {X1[i], X1[i]}, x2 = {X2[i], X2[i]};
            v2f d = __builtin_elementwise_fma(x0, Y0,
                    __builtin_elementwise_fma(x1, Y1,
                    __builtin_elementwise_fma(x2, Y2, YS)));
            M[i] = fminf(fminf(M[i], d.x), d.y);   // v_min3_f32
        }
    }

    float* plane = wspart + (size_t)qs * NMIN;
    int slot = (dir * NB + n) * PP + pc * PCHUNK + t;
    #pragma unroll
    for (int i = 0; i < NPTS; ++i)
        plane[slot + i * 256] = M[i] + XS[i];   // coalesced, no atomics, no init
}

// ---------------- reduce planes + log2sum + finalize (fused) ----------------
// grid = 256 blocks x 256 threads; slot t = blockIdx.x*256+threadIdx.x.
// Blocks 0..127 cover dir0 slots, 128..255 dir1. Blocks 0..63 also do log2.
// Last-done block finalizes the 5 outputs.
__global__ __launch_bounds__(256) void reduce_kernel(const float* __restrict__ wspart,
                                                     const float* __restrict__ lik,
                                                     float* __restrict__ wssum,  // [0],[1],[2]=sums, [3]=ticket
                                                     float* __restrict__ out) {
    int t = blockIdx.x * 256 + threadIdx.x;
    float m = wspart[t];
    #pragma unroll
    for (int s = 1; s < QSLICES; ++s)
        m = fminf(m, wspart[(size_t)s * NMIN + t]);

    float l = 0.f;
    if (t < NLIK) l = __log2f(lik[t]);

    #pragma unroll
    for (int off = 32; off > 0; off >>= 1) {
        m += __shfl_down(m, off, 64);
        l += __shfl_down(l, off, 64);
    }
    __shared__ float rm[4], rl[4];
    int lane = threadIdx.x & 63, wid = threadIdx.x >> 6;
    if (lane == 0) { rm[wid] = m; rl[wid] = l; }
    __syncthreads();
    if (threadIdx.x == 0) {
        int dir = blockIdx.x >> 7;
        atomicAdd(&wssum[dir], rm[0] + rm[1] + rm[2] + rm[3]);
        if (blockIdx.x < 64)
            atomicAdd(&wssum[2], rl[0] + rl[1] + rl[2] + rl[3]);
        __threadfence();
        unsigned done = atomicAdd((unsigned*)&wssum[3], 1u);
        if (done == 255u) {
            __threadfence();
            float s0 = __hip_atomic_load(&wssum[0], __ATOMIC_ACQUIRE, __HIP_MEMORY_SCOPE_AGENT);
            float s1 = __hip_atomic_load(&wssum[1], __ATOMIC_ACQUIRE, __HIP_MEMORY_SCOPE_AGENT);
            float s2 = __hip_atomic_load(&wssum[2], __ATOMIC_ACQUIRE, __HIP_MEMORY_SCOPE_AGENT);
            float rec = s0 / (float)(NB * PP) + s1 / (float)(NB * PP);
            float bit_y = s2 / (-(float)NB);
            float bpp = bit_y / (float)PP;
            out[0] = bpp + 1.0f * rec;  // loss (LMBDA = 1)
            out[1] = bpp;               // bpp_loss
            out[2] = rec;               // rec_loss
            out[3] = bit_y;             // bit_loss
            out[4] = bpp;               // bpp_y
        }
    }
}

extern "C" void kernel_launch(void* const* d_in, const int* in_sizes, int n_in,
                              void* d_out, int out_size, void* d_ws, size_t ws_size,
                              hipStream_t stream) {
    const float* x_hat  = (const float*)d_in[0];
    const float* points = (const float*)d_in[1];
    const float* lik    = (const float*)d_in[2];
    float* out = (float*)d_out;
    float* wssum  = (float*)d_ws;          // 4 floats: sums + ticket
    float* wspart = (float*)d_ws + 16;     // 16 planes x 65536 floats = 4 MB

    hipMemsetAsync(wssum, 0, 16, stream);  // sums + ticket only
    chamfer_kernel<<<DIRS * NB * NPBLK * QSLICES, 256, 0, stream>>>(x_hat, points, wspart);
    reduce_kernel<<<256, 256, 0, stream>>>(wspart, lik, wssum, out);
}